// Round 3
// baseline (719.198 us; speedup 1.0000x reference)
//
#include <hip/hip_runtime.h>
#include <cstdint>
#include <cstddef>

#define D 128

// ---------------- Threefry-2x32 (JAX/Random123), host+device ----------------
__host__ __device__ inline uint32_t rotl32(uint32_t v, int d) {
  return (v << d) | (v >> (32 - d));
}

__host__ __device__ inline void threefry2x32(uint32_t k0, uint32_t k1,
                                             uint32_t x0, uint32_t x1,
                                             uint32_t* o0, uint32_t* o1) {
  uint32_t k2 = k0 ^ k1 ^ 0x1BD11BDAu;
  x0 += k0; x1 += k1;
#define TF_RND(r) x0 += x1; x1 = rotl32(x1, (r)); x1 ^= x0;
  TF_RND(13) TF_RND(15) TF_RND(26) TF_RND(6)
  x0 += k1; x1 += k2 + 1u;
  TF_RND(17) TF_RND(29) TF_RND(16) TF_RND(24)
  x0 += k2; x1 += k0 + 2u;
  TF_RND(13) TF_RND(15) TF_RND(26) TF_RND(6)
  x0 += k0; x1 += k1 + 3u;
  TF_RND(17) TF_RND(29) TF_RND(16) TF_RND(24)
  x0 += k1; x1 += k2 + 4u;
  TF_RND(13) TF_RND(15) TF_RND(26) TF_RND(6)
  x0 += k2; x1 += k0 + 5u;
#undef TF_RND
  *o0 = x0; *o1 = x1;
}

// XLA ErfInv32 (Giles) — matches lax.erf_inv lowering for f32.
__device__ inline float erfinv_f32(float x) {
  float w = -log1pf(-x * x);
  float p;
  if (w < 5.0f) {
    w = w - 2.5f;
    p = 2.81022636e-08f;
    p = fmaf(p, w, 3.43273939e-07f);
    p = fmaf(p, w, -3.5233877e-06f);
    p = fmaf(p, w, -4.39150654e-06f);
    p = fmaf(p, w, 0.00021858087f);
    p = fmaf(p, w, -0.00125372503f);
    p = fmaf(p, w, -0.00417768164f);
    p = fmaf(p, w, 0.246640727f);
    p = fmaf(p, w, 1.50140941f);
  } else {
    w = sqrtf(w) - 3.0f;
    p = -0.000200214257f;
    p = fmaf(p, w, 0.000100950558f);
    p = fmaf(p, w, 0.00134934322f);
    p = fmaf(p, w, -0.00367342844f);
    p = fmaf(p, w, 0.00573950773f);
    p = fmaf(p, w, -0.0076224613f);
    p = fmaf(p, w, 0.00943887047f);
    p = fmaf(p, w, 1.00167406f);
    p = fmaf(p, w, 2.83297682f);
  }
  return p * x;
}

__device__ inline float jax_normal_elem(uint32_t k0, uint32_t k1, uint32_t idx) {
  uint32_t o0, o1;
  threefry2x32(k0, k1, 0u, idx, &o0, &o1);
  uint32_t bits = o0 ^ o1;
  float f = __uint_as_float((bits >> 9) | 0x3F800000u) - 1.0f;  // [0,1)
  float u = f * 2.0f + (-0.99999994f);
  u = fmaxf(-0.99999994f, u);
  return 1.41421356237309505f * erfinv_f32(u);
}

// ---------------- CSR build -------------------------------------------------
__global__ __launch_bounds__(256) void hist_kernel(
    const int* __restrict__ dst, int* __restrict__ counts, int E) {
  int t = blockIdx.x * blockDim.x + threadIdx.x;
  if (t < E) atomicAdd(&counts[dst[t]], 1);
}

// In-place per-block exclusive scan of counts[0..N); blocksums[b] = block total.
__global__ __launch_bounds__(256) void scanA_kernel(
    int* __restrict__ counts, int* __restrict__ blocksums, int N) {
  __shared__ int tmp[256];
  int tid = threadIdx.x;
  int i = blockIdx.x * 256 + tid;
  int v = (i < N) ? counts[i] : 0;
  tmp[tid] = v;
  __syncthreads();
  for (int off = 1; off < 256; off <<= 1) {
    int t = (tid >= off) ? tmp[tid - off] : 0;
    __syncthreads();
    tmp[tid] += t;
    __syncthreads();
  }
  if (i < N) counts[i] = tmp[tid] - v;  // exclusive
  if (tid == 255) blocksums[blockIdx.x] = tmp[tid];
}

// Exclusive scan of blocksums[nb] (nb <= 256), single block.
__global__ __launch_bounds__(256) void scanB_kernel(
    int* __restrict__ blocksums, int nb) {
  __shared__ int tmp[256];
  int tid = threadIdx.x;
  int v = (tid < nb) ? blocksums[tid] : 0;
  tmp[tid] = v;
  __syncthreads();
  for (int off = 1; off < 256; off <<= 1) {
    int t = (tid >= off) ? tmp[tid - off] : 0;
    __syncthreads();
    tmp[tid] += t;
    __syncthreads();
  }
  if (tid < nb) blocksums[tid] = tmp[tid] - v;
}

// offsets[i] += blocksums[b]; cursor copy; offsets[N]=E.
__global__ __launch_bounds__(256) void scanC_kernel(
    int* __restrict__ offsets, int* __restrict__ cursor,
    const int* __restrict__ blocksums, int N, int E) {
  int i = blockIdx.x * 256 + threadIdx.x;
  if (i < N) {
    int o = offsets[i] + blocksums[blockIdx.x];
    offsets[i] = o;
    cursor[i] = o;
  }
  if (i == 0) offsets[N] = E;
}

// Degree histogram (degrees from completed offsets).
__global__ __launch_bounds__(256) void deghist_kernel(
    const int* __restrict__ offsets, int* __restrict__ deg_hist, int N) {
  int i = blockIdx.x * 256 + threadIdx.x;
  if (i < N) {
    int d = min(offsets[i + 1] - offsets[i], 1023);
    atomicAdd(&deg_hist[d], 1);
  }
}

// Exclusive scan of 1024 bins -> deg_cursor; single block, 4 bins/thread.
__global__ __launch_bounds__(256) void degscan_kernel(
    const int* __restrict__ deg_hist, int* __restrict__ deg_cursor) {
  __shared__ int tmp[256];
  int tid = threadIdx.x;
  int loc[4], s = 0;
#pragma unroll
  for (int k = 0; k < 4; ++k) { loc[k] = deg_hist[tid * 4 + k]; s += loc[k]; }
  tmp[tid] = s;
  __syncthreads();
  for (int off = 1; off < 256; off <<= 1) {
    int t = (tid >= off) ? tmp[tid - off] : 0;
    __syncthreads();
    tmp[tid] += t;
    __syncthreads();
  }
  int run = tmp[tid] - s;
#pragma unroll
  for (int k = 0; k < 4; ++k) { deg_cursor[tid * 4 + k] = run; run += loc[k]; }
}

// perm = rows in ascending-degree order.
__global__ __launch_bounds__(256) void degscatter_kernel(
    const int* __restrict__ offsets, int* __restrict__ deg_cursor,
    int* __restrict__ perm, int N) {
  int i = blockIdx.x * 256 + threadIdx.x;
  if (i < N) {
    int d = min(offsets[i + 1] - offsets[i], 1023);
    int pos = atomicAdd(&deg_cursor[d], 1);
    perm[pos] = i;
  }
}

__global__ __launch_bounds__(256) void edgescatter_kernel(
    const int* __restrict__ src, const int* __restrict__ dst,
    int* __restrict__ cursor, int* __restrict__ sorted_src, int E) {
  int t = blockIdx.x * blockDim.x + threadIdx.x;
  if (t < E) {
    int d = dst[t];
    int pos = atomicAdd(&cursor[d], 1);
    sorted_src[pos] = src[t];
  }
}

// ---------------- out[0] = normalize(x): one wave per row -------------------
__global__ __launch_bounds__(256) void norm_kernel(
    const float* __restrict__ in, float* __restrict__ out, int N) {
  int t = blockIdx.x * blockDim.x + threadIdx.x;
  int row = t >> 6;
  int lane = t & 63;
  if (row >= N) return;
  size_t base = (size_t)row * D + 2 * lane;
  float2 v = *(const float2*)(in + base);
  float ss = v.x * v.x + v.y * v.y;
#pragma unroll
  for (int off = 32; off > 0; off >>= 1) ss += __shfl_xor(ss, off);
  float denom = fmaxf(sqrtf(ss), 1e-12f);
  *(float2*)(out + base) = make_float2(v.x / denom, v.y / denom);
}

// ---------------- Fused hop: 8 lanes/row, 8 rows/wave -----------------------
union V16 { float4 v[4]; float f[16]; };

__global__ __launch_bounds__(256) void hop_kernel(
    const float* __restrict__ hprev, float* __restrict__ hout,
    const int* __restrict__ offsets, const int* __restrict__ sorted_src,
    const int* __restrict__ perm, int N, uint32_t k0, uint32_t k1) {
  int g = (blockIdx.x * blockDim.x + threadIdx.x) >> 3;  // group = one dst row
  int sub = threadIdx.x & 7;                             // 8 lanes per row
  if (g >= N) return;
  int r = perm[g];
  size_t rbase = (size_t)r * D + sub * 16;

  V16 b;
  {
    const float4* p = (const float4*)(hprev + rbase);
    b.v[0] = p[0]; b.v[1] = p[1]; b.v[2] = p[2]; b.v[3] = p[3];
  }
  V16 acc;
#pragma unroll
  for (int i = 0; i < 16; ++i) acc.f[i] = 0.f;

  int j = offsets[r], jhi = offsets[r + 1];
  V16 a;
  if (j < jhi) {
    const float4* p = (const float4*)(hprev + (size_t)sorted_src[j] * D + sub * 16);
    a.v[0] = p[0]; a.v[1] = p[1]; a.v[2] = p[2]; a.v[3] = p[3];
  }
  while (j < jhi) {
    int jn = j + 1;
    V16 an;
    if (jn < jhi) {
      const float4* p = (const float4*)(hprev + (size_t)sorted_src[jn] * D + sub * 16);
      an.v[0] = p[0]; an.v[1] = p[1]; an.v[2] = p[2]; an.v[3] = p[3];
    }
    float part = a.f[0] * b.f[0];
#pragma unroll
    for (int i = 1; i < 16; ++i) part = fmaf(a.f[i], b.f[i], part);
    part += __shfl_xor(part, 1);
    part += __shfl_xor(part, 2);
    part += __shfl_xor(part, 4);
    float alpha = 1.0f / (1.0f + expf(-part));
#pragma unroll
    for (int i = 0; i < 16; ++i) acc.f[i] = fmaf(alpha, a.f[i], acc.f[i]);
    a = an;
    j = jn;
  }

  // noise (bit-exact jax.random.normal) + L2 normalize epilogue
  uint32_t idx = (uint32_t)rbase;
  float ss = 0.f;
#pragma unroll
  for (int i = 0; i < 16; ++i) {
    acc.f[i] += 0.1f * jax_normal_elem(k0, k1, idx + (uint32_t)i);
    ss = fmaf(acc.f[i], acc.f[i], ss);
  }
  ss += __shfl_xor(ss, 1);
  ss += __shfl_xor(ss, 2);
  ss += __shfl_xor(ss, 4);
  float denom = fmaxf(sqrtf(ss), 1e-12f);
#pragma unroll
  for (int i = 0; i < 16; ++i) acc.f[i] = acc.f[i] / denom;
  {
    float4* p = (float4*)(hout + rbase);
    p[0] = acc.v[0]; p[1] = acc.v[1]; p[2] = acc.v[2]; p[3] = acc.v[3];
  }
}

extern "C" void kernel_launch(void* const* d_in, const int* in_sizes, int n_in,
                              void* d_out, int out_size, void* d_ws, size_t ws_size,
                              hipStream_t stream) {
  const float* x = (const float*)d_in[0];
  const int* ei = (const int*)d_in[1];
  int N = in_sizes[0] / D;   // 50000
  int E = in_sizes[1] / 2;   // 800000
  const int* src = ei;
  const int* dst = ei + E;
  float* out = (float*)d_out;
  size_t ND = (size_t)N * D;

  int nblocksN = (N + 255) / 256;

  // ws layout (ints): offsets[N+1] | cursor[N] | perm[N] | deg_hist[1024]
  //                 | deg_cursor[1024] | blocksums[256 pad] | sorted_src[E]
  int* offsets = (int*)d_ws;
  int* cursor = offsets + (N + 1);
  int* perm = cursor + N;
  int* deg_hist = perm + N;
  int* deg_cursor = deg_hist + 1024;
  int* blocksums = deg_cursor + 1024;
  int* sorted_src = blocksums + 256;

  // noise_keys = jax.random.split(jax.random.key(1), 3)  [threefry_partitionable]
  uint32_t nk0[3], nk1[3];
  for (int k = 0; k < 3; ++k)
    threefry2x32(0u, 1u, 0u, (uint32_t)k, &nk0[k], &nk1[k]);

  int eBlocks = (E + 255) / 256;
  int rowWaveBlocks = (int)(((size_t)N * 64 + 255) / 256);  // 1 wave/row (norm)
  int hopBlocks = (int)(((size_t)N * 8 + 255) / 256);       // 8 lanes/row (hop)

  // ---- CSR build + degree sort (reused by all 3 hops) ----
  hipMemsetAsync(offsets, 0, (size_t)(N + 1) * sizeof(int), stream);
  hipMemsetAsync(deg_hist, 0, 1024 * sizeof(int), stream);
  hipLaunchKernelGGL(hist_kernel, dim3(eBlocks), dim3(256), 0, stream, dst, offsets, E);
  hipLaunchKernelGGL(scanA_kernel, dim3(nblocksN), dim3(256), 0, stream,
                     offsets, blocksums, N);
  hipLaunchKernelGGL(scanB_kernel, dim3(1), dim3(256), 0, stream, blocksums, nblocksN);
  hipLaunchKernelGGL(scanC_kernel, dim3(nblocksN), dim3(256), 0, stream,
                     offsets, cursor, blocksums, N, E);
  hipLaunchKernelGGL(deghist_kernel, dim3(nblocksN), dim3(256), 0, stream,
                     offsets, deg_hist, N);
  hipLaunchKernelGGL(degscan_kernel, dim3(1), dim3(256), 0, stream,
                     deg_hist, deg_cursor);
  hipLaunchKernelGGL(degscatter_kernel, dim3(nblocksN), dim3(256), 0, stream,
                     offsets, deg_cursor, perm, N);
  hipLaunchKernelGGL(edgescatter_kernel, dim3(eBlocks), dim3(256), 0, stream,
                     src, dst, cursor, sorted_src, E);

  // out[0] = normalize(x)
  hipLaunchKernelGGL(norm_kernel, dim3(rowWaveBlocks), dim3(256), 0, stream, x, out, N);

  for (int k = 0; k < 3; ++k) {
    const float* hk = out + (size_t)k * ND;
    float* hk1 = out + (size_t)(k + 1) * ND;
    hipLaunchKernelGGL(hop_kernel, dim3(hopBlocks), dim3(256), 0, stream,
                       hk, hk1, offsets, sorted_src, perm, N, nk0[k], nk1[k]);
  }
}

// Round 4
// 484.768 us; speedup vs baseline: 1.4836x; 1.4836x over previous
//
#include <hip/hip_runtime.h>
#include <cstdint>
#include <cstddef>

#define D 128

// ---------------- Threefry-2x32 (JAX/Random123), host+device ----------------
__host__ __device__ inline uint32_t rotl32(uint32_t v, int d) {
  return (v << d) | (v >> (32 - d));
}

__host__ __device__ inline void threefry2x32(uint32_t k0, uint32_t k1,
                                             uint32_t x0, uint32_t x1,
                                             uint32_t* o0, uint32_t* o1) {
  uint32_t k2 = k0 ^ k1 ^ 0x1BD11BDAu;
  x0 += k0; x1 += k1;
#define TF_RND(r) x0 += x1; x1 = rotl32(x1, (r)); x1 ^= x0;
  TF_RND(13) TF_RND(15) TF_RND(26) TF_RND(6)
  x0 += k1; x1 += k2 + 1u;
  TF_RND(17) TF_RND(29) TF_RND(16) TF_RND(24)
  x0 += k2; x1 += k0 + 2u;
  TF_RND(13) TF_RND(15) TF_RND(26) TF_RND(6)
  x0 += k0; x1 += k1 + 3u;
  TF_RND(17) TF_RND(29) TF_RND(16) TF_RND(24)
  x0 += k1; x1 += k2 + 4u;
  TF_RND(13) TF_RND(15) TF_RND(26) TF_RND(6)
  x0 += k2; x1 += k0 + 5u;
#undef TF_RND
  *o0 = x0; *o1 = x1;
}

// XLA ErfInv32 (Giles) — matches lax.erf_inv lowering for f32.
__device__ inline float erfinv_f32(float x) {
  float w = -log1pf(-x * x);
  float p;
  if (w < 5.0f) {
    w = w - 2.5f;
    p = 2.81022636e-08f;
    p = fmaf(p, w, 3.43273939e-07f);
    p = fmaf(p, w, -3.5233877e-06f);
    p = fmaf(p, w, -4.39150654e-06f);
    p = fmaf(p, w, 0.00021858087f);
    p = fmaf(p, w, -0.00125372503f);
    p = fmaf(p, w, -0.00417768164f);
    p = fmaf(p, w, 0.246640727f);
    p = fmaf(p, w, 1.50140941f);
  } else {
    w = sqrtf(w) - 3.0f;
    p = -0.000200214257f;
    p = fmaf(p, w, 0.000100950558f);
    p = fmaf(p, w, 0.00134934322f);
    p = fmaf(p, w, -0.00367342844f);
    p = fmaf(p, w, 0.00573950773f);
    p = fmaf(p, w, -0.0076224613f);
    p = fmaf(p, w, 0.00943887047f);
    p = fmaf(p, w, 1.00167406f);
    p = fmaf(p, w, 2.83297682f);
  }
  return p * x;
}

__device__ inline float jax_normal_elem(uint32_t k0, uint32_t k1, uint32_t idx) {
  uint32_t o0, o1;
  threefry2x32(k0, k1, 0u, idx, &o0, &o1);
  uint32_t bits = o0 ^ o1;
  float f = __uint_as_float((bits >> 9) | 0x3F800000u) - 1.0f;  // [0,1)
  float u = f * 2.0f + (-0.99999994f);
  u = fmaxf(-0.99999994f, u);
  return 1.41421356237309505f * erfinv_f32(u);
}

// ---------------- CSR build -------------------------------------------------
__global__ __launch_bounds__(256) void hist_kernel(
    const int* __restrict__ dst, int* __restrict__ counts, int E) {
  int t = blockIdx.x * blockDim.x + threadIdx.x;
  if (t < E) atomicAdd(&counts[dst[t]], 1);
}

// In-place per-block exclusive scan of counts[0..N); blocksums[b] = block total.
__global__ __launch_bounds__(256) void scanA_kernel(
    int* __restrict__ counts, int* __restrict__ blocksums, int N) {
  __shared__ int tmp[256];
  int tid = threadIdx.x;
  int i = blockIdx.x * 256 + tid;
  int v = (i < N) ? counts[i] : 0;
  tmp[tid] = v;
  __syncthreads();
  for (int off = 1; off < 256; off <<= 1) {
    int t = (tid >= off) ? tmp[tid - off] : 0;
    __syncthreads();
    tmp[tid] += t;
    __syncthreads();
  }
  if (i < N) counts[i] = tmp[tid] - v;  // exclusive
  if (tid == 255) blocksums[blockIdx.x] = tmp[tid];
}

// Exclusive scan of blocksums[nb] (nb <= 256), single block.
__global__ __launch_bounds__(256) void scanB_kernel(
    int* __restrict__ blocksums, int nb) {
  __shared__ int tmp[256];
  int tid = threadIdx.x;
  int v = (tid < nb) ? blocksums[tid] : 0;
  tmp[tid] = v;
  __syncthreads();
  for (int off = 1; off < 256; off <<= 1) {
    int t = (tid >= off) ? tmp[tid - off] : 0;
    __syncthreads();
    tmp[tid] += t;
    __syncthreads();
  }
  if (tid < nb) blocksums[tid] = tmp[tid] - v;
}

// offsets[i] += blocksums[b]; cursor copy; offsets[N]=E.
__global__ __launch_bounds__(256) void scanC_kernel(
    int* __restrict__ offsets, int* __restrict__ cursor,
    const int* __restrict__ blocksums, int N, int E) {
  int i = blockIdx.x * 256 + threadIdx.x;
  if (i < N) {
    int o = offsets[i] + blocksums[blockIdx.x];
    offsets[i] = o;
    cursor[i] = o;
  }
  if (i == 0) offsets[N] = E;
}

// Degree histogram — LDS-aggregated (global bins are ~45 hot addresses;
// naive global atomics serialized ~1100 threads/address → 100+ us).
__global__ __launch_bounds__(256) void deghist_kernel(
    const int* __restrict__ offsets, int* __restrict__ deg_hist, int N) {
  __shared__ int lhist[1024];
  for (int b = threadIdx.x; b < 1024; b += 256) lhist[b] = 0;
  __syncthreads();
  int i = blockIdx.x * 256 + threadIdx.x;
  if (i < N) {
    int d = min(offsets[i + 1] - offsets[i], 1023);
    atomicAdd(&lhist[d], 1);
  }
  __syncthreads();
  for (int b = threadIdx.x; b < 1024; b += 256) {
    int c = lhist[b];
    if (c) atomicAdd(&deg_hist[b], c);
  }
}

// Exclusive scan of 1024 bins -> deg_cursor; single block, 4 bins/thread.
__global__ __launch_bounds__(256) void degscan_kernel(
    const int* __restrict__ deg_hist, int* __restrict__ deg_cursor) {
  __shared__ int tmp[256];
  int tid = threadIdx.x;
  int loc[4], s = 0;
#pragma unroll
  for (int k = 0; k < 4; ++k) { loc[k] = deg_hist[tid * 4 + k]; s += loc[k]; }
  tmp[tid] = s;
  __syncthreads();
  for (int off = 1; off < 256; off <<= 1) {
    int t = (tid >= off) ? tmp[tid - off] : 0;
    __syncthreads();
    tmp[tid] += t;
    __syncthreads();
  }
  int run = tmp[tid] - s;
#pragma unroll
  for (int k = 0; k < 4; ++k) { deg_cursor[tid * 4 + k] = run; run += loc[k]; }
}

// perm = rows grouped by degree — LDS-aggregated scatter: one LDS-local
// position per row, one global atomic per populated bin per block.
__global__ __launch_bounds__(256) void degscatter_kernel(
    const int* __restrict__ offsets, int* __restrict__ deg_cursor,
    int* __restrict__ perm, int N) {
  __shared__ int lhist[1024];
  __shared__ int lbase[1024];
  for (int b = threadIdx.x; b < 1024; b += 256) lhist[b] = 0;
  __syncthreads();
  int i = blockIdx.x * 256 + threadIdx.x;
  int d = 0, lpos = 0;
  if (i < N) {
    d = min(offsets[i + 1] - offsets[i], 1023);
    lpos = atomicAdd(&lhist[d], 1);
  }
  __syncthreads();
  for (int b = threadIdx.x; b < 1024; b += 256) {
    int c = lhist[b];
    lbase[b] = c ? atomicAdd(&deg_cursor[b], c) : 0;
  }
  __syncthreads();
  if (i < N) perm[lbase[d] + lpos] = i;
}

__global__ __launch_bounds__(256) void edgescatter_kernel(
    const int* __restrict__ src, const int* __restrict__ dst,
    int* __restrict__ cursor, int* __restrict__ sorted_src, int E) {
  int t = blockIdx.x * blockDim.x + threadIdx.x;
  if (t < E) {
    int d = dst[t];
    int pos = atomicAdd(&cursor[d], 1);
    sorted_src[pos] = src[t];
  }
}

// ---------------- out[0] = normalize(x): one wave per row -------------------
__global__ __launch_bounds__(256) void norm_kernel(
    const float* __restrict__ in, float* __restrict__ out, int N) {
  int t = blockIdx.x * blockDim.x + threadIdx.x;
  int row = t >> 6;
  int lane = t & 63;
  if (row >= N) return;
  size_t base = (size_t)row * D + 2 * lane;
  float2 v = *(const float2*)(in + base);
  float ss = v.x * v.x + v.y * v.y;
#pragma unroll
  for (int off = 32; off > 0; off >>= 1) ss += __shfl_xor(ss, off);
  float denom = fmaxf(sqrtf(ss), 1e-12f);
  *(float2*)(out + base) = make_float2(v.x / denom, v.y / denom);
}

// ---------------- Fused hop: 8 lanes/row, 8 rows/wave -----------------------
union V16 { float4 v[4]; float f[16]; };

__global__ __launch_bounds__(256) void hop_kernel(
    const float* __restrict__ hprev, float* __restrict__ hout,
    const int* __restrict__ offsets, const int* __restrict__ sorted_src,
    const int* __restrict__ perm, int N, uint32_t k0, uint32_t k1) {
  int g = (blockIdx.x * blockDim.x + threadIdx.x) >> 3;  // group = one dst row
  int sub = threadIdx.x & 7;                             // 8 lanes per row
  if (g >= N) return;
  int r = perm[g];
  size_t rbase = (size_t)r * D + sub * 16;

  V16 b;
  {
    const float4* p = (const float4*)(hprev + rbase);
    b.v[0] = p[0]; b.v[1] = p[1]; b.v[2] = p[2]; b.v[3] = p[3];
  }
  V16 acc;
#pragma unroll
  for (int i = 0; i < 16; ++i) acc.f[i] = 0.f;

  int j = offsets[r], jhi = offsets[r + 1];
  V16 a;
  if (j < jhi) {
    const float4* p = (const float4*)(hprev + (size_t)sorted_src[j] * D + sub * 16);
    a.v[0] = p[0]; a.v[1] = p[1]; a.v[2] = p[2]; a.v[3] = p[3];
  }
  while (j < jhi) {
    int jn = j + 1;
    V16 an;
    if (jn < jhi) {
      const float4* p = (const float4*)(hprev + (size_t)sorted_src[jn] * D + sub * 16);
      an.v[0] = p[0]; an.v[1] = p[1]; an.v[2] = p[2]; an.v[3] = p[3];
    }
    float part = a.f[0] * b.f[0];
#pragma unroll
    for (int i = 1; i < 16; ++i) part = fmaf(a.f[i], b.f[i], part);
    part += __shfl_xor(part, 1);
    part += __shfl_xor(part, 2);
    part += __shfl_xor(part, 4);
    float alpha = 1.0f / (1.0f + expf(-part));
#pragma unroll
    for (int i = 0; i < 16; ++i) acc.f[i] = fmaf(alpha, a.f[i], acc.f[i]);
    a = an;
    j = jn;
  }

  // noise (bit-exact jax.random.normal) + L2 normalize epilogue
  uint32_t idx = (uint32_t)rbase;
  float ss = 0.f;
#pragma unroll
  for (int i = 0; i < 16; ++i) {
    acc.f[i] += 0.1f * jax_normal_elem(k0, k1, idx + (uint32_t)i);
    ss = fmaf(acc.f[i], acc.f[i], ss);
  }
  ss += __shfl_xor(ss, 1);
  ss += __shfl_xor(ss, 2);
  ss += __shfl_xor(ss, 4);
  float denom = fmaxf(sqrtf(ss), 1e-12f);
#pragma unroll
  for (int i = 0; i < 16; ++i) acc.f[i] = acc.f[i] / denom;
  {
    float4* p = (float4*)(hout + rbase);
    p[0] = acc.v[0]; p[1] = acc.v[1]; p[2] = acc.v[2]; p[3] = acc.v[3];
  }
}

extern "C" void kernel_launch(void* const* d_in, const int* in_sizes, int n_in,
                              void* d_out, int out_size, void* d_ws, size_t ws_size,
                              hipStream_t stream) {
  const float* x = (const float*)d_in[0];
  const int* ei = (const int*)d_in[1];
  int N = in_sizes[0] / D;   // 50000
  int E = in_sizes[1] / 2;   // 800000
  const int* src = ei;
  const int* dst = ei + E;
  float* out = (float*)d_out;
  size_t ND = (size_t)N * D;

  int nblocksN = (N + 255) / 256;

  // ws layout (ints): offsets[N+1] | cursor[N] | perm[N] | deg_hist[1024]
  //                 | deg_cursor[1024] | blocksums[256 pad] | sorted_src[E]
  int* offsets = (int*)d_ws;
  int* cursor = offsets + (N + 1);
  int* perm = cursor + N;
  int* deg_hist = perm + N;
  int* deg_cursor = deg_hist + 1024;
  int* blocksums = deg_cursor + 1024;
  int* sorted_src = blocksums + 256;

  // noise_keys = jax.random.split(jax.random.key(1), 3)  [threefry_partitionable]
  uint32_t nk0[3], nk1[3];
  for (int k = 0; k < 3; ++k)
    threefry2x32(0u, 1u, 0u, (uint32_t)k, &nk0[k], &nk1[k]);

  int eBlocks = (E + 255) / 256;
  int rowWaveBlocks = (int)(((size_t)N * 64 + 255) / 256);  // 1 wave/row (norm)
  int hopBlocks = (int)(((size_t)N * 8 + 255) / 256);       // 8 lanes/row (hop)

  // ---- CSR build + degree sort (reused by all 3 hops) ----
  hipMemsetAsync(offsets, 0, (size_t)(N + 1) * sizeof(int), stream);
  hipMemsetAsync(deg_hist, 0, 1024 * sizeof(int), stream);
  hipLaunchKernelGGL(hist_kernel, dim3(eBlocks), dim3(256), 0, stream, dst, offsets, E);
  hipLaunchKernelGGL(scanA_kernel, dim3(nblocksN), dim3(256), 0, stream,
                     offsets, blocksums, N);
  hipLaunchKernelGGL(scanB_kernel, dim3(1), dim3(256), 0, stream, blocksums, nblocksN);
  hipLaunchKernelGGL(scanC_kernel, dim3(nblocksN), dim3(256), 0, stream,
                     offsets, cursor, blocksums, N, E);
  hipLaunchKernelGGL(deghist_kernel, dim3(nblocksN), dim3(256), 0, stream,
                     offsets, deg_hist, N);
  hipLaunchKernelGGL(degscan_kernel, dim3(1), dim3(256), 0, stream,
                     deg_hist, deg_cursor);
  hipLaunchKernelGGL(degscatter_kernel, dim3(nblocksN), dim3(256), 0, stream,
                     offsets, deg_cursor, perm, N);
  hipLaunchKernelGGL(edgescatter_kernel, dim3(eBlocks), dim3(256), 0, stream,
                     src, dst, cursor, sorted_src, E);

  // out[0] = normalize(x)
  hipLaunchKernelGGL(norm_kernel, dim3(rowWaveBlocks), dim3(256), 0, stream, x, out, N);

  for (int k = 0; k < 3; ++k) {
    const float* hk = out + (size_t)k * ND;
    float* hk1 = out + (size_t)(k + 1) * ND;
    hipLaunchKernelGGL(hop_kernel, dim3(hopBlocks), dim3(256), 0, stream,
                       hk, hk1, offsets, sorted_src, perm, N, nk0[k], nk1[k]);
  }
}

// Round 5
// 441.658 us; speedup vs baseline: 1.6284x; 1.0976x over previous
//
#include <hip/hip_runtime.h>
#include <cstdint>
#include <cstddef>

#define D 128

// ---------------- Threefry-2x32 (JAX/Random123), host+device ----------------
__host__ __device__ inline uint32_t rotl32(uint32_t v, int d) {
  return (v << d) | (v >> (32 - d));
}

__host__ __device__ inline void threefry2x32(uint32_t k0, uint32_t k1,
                                             uint32_t x0, uint32_t x1,
                                             uint32_t* o0, uint32_t* o1) {
  uint32_t k2 = k0 ^ k1 ^ 0x1BD11BDAu;
  x0 += k0; x1 += k1;
#define TF_RND(r) x0 += x1; x1 = rotl32(x1, (r)); x1 ^= x0;
  TF_RND(13) TF_RND(15) TF_RND(26) TF_RND(6)
  x0 += k1; x1 += k2 + 1u;
  TF_RND(17) TF_RND(29) TF_RND(16) TF_RND(24)
  x0 += k2; x1 += k0 + 2u;
  TF_RND(13) TF_RND(15) TF_RND(26) TF_RND(6)
  x0 += k0; x1 += k1 + 3u;
  TF_RND(17) TF_RND(29) TF_RND(16) TF_RND(24)
  x0 += k1; x1 += k2 + 4u;
  TF_RND(13) TF_RND(15) TF_RND(26) TF_RND(6)
  x0 += k2; x1 += k0 + 5u;
#undef TF_RND
  *o0 = x0; *o1 = x1;
}

// XLA ErfInv32 (Giles) — matches lax.erf_inv lowering for f32.
__device__ inline float erfinv_f32(float x) {
  float w = -log1pf(-x * x);
  float p;
  if (w < 5.0f) {
    w = w - 2.5f;
    p = 2.81022636e-08f;
    p = fmaf(p, w, 3.43273939e-07f);
    p = fmaf(p, w, -3.5233877e-06f);
    p = fmaf(p, w, -4.39150654e-06f);
    p = fmaf(p, w, 0.00021858087f);
    p = fmaf(p, w, -0.00125372503f);
    p = fmaf(p, w, -0.00417768164f);
    p = fmaf(p, w, 0.246640727f);
    p = fmaf(p, w, 1.50140941f);
  } else {
    w = sqrtf(w) - 3.0f;
    p = -0.000200214257f;
    p = fmaf(p, w, 0.000100950558f);
    p = fmaf(p, w, 0.00134934322f);
    p = fmaf(p, w, -0.00367342844f);
    p = fmaf(p, w, 0.00573950773f);
    p = fmaf(p, w, -0.0076224613f);
    p = fmaf(p, w, 0.00943887047f);
    p = fmaf(p, w, 1.00167406f);
    p = fmaf(p, w, 2.83297682f);
  }
  return p * x;
}

__device__ inline float jax_normal_elem(uint32_t k0, uint32_t k1, uint32_t idx) {
  uint32_t o0, o1;
  threefry2x32(k0, k1, 0u, idx, &o0, &o1);
  uint32_t bits = o0 ^ o1;
  float f = __uint_as_float((bits >> 9) | 0x3F800000u) - 1.0f;  // [0,1)
  float u = f * 2.0f + (-0.99999994f);
  u = fmaxf(-0.99999994f, u);
  return 1.41421356237309505f * erfinv_f32(u);
}

__device__ inline uint32_t f32_to_bf16_rne(float f) {
  uint32_t u = __float_as_uint(f);
  u += 0x7fffu + ((u >> 16) & 1u);
  return u >> 16;
}

// ---------------- CSR build -------------------------------------------------
__global__ __launch_bounds__(256) void hist4_kernel(
    const int* __restrict__ dst, int* __restrict__ counts, int E4, int E) {
  int t = blockIdx.x * blockDim.x + threadIdx.x;
  if (t < E4) {
    int4 d = ((const int4*)dst)[t];
    atomicAdd(&counts[d.x], 1);
    atomicAdd(&counts[d.y], 1);
    atomicAdd(&counts[d.z], 1);
    atomicAdd(&counts[d.w], 1);
  }
  int rem = E4 * 4 + t;
  if (t < E - E4 * 4) atomicAdd(&counts[dst[rem]], 1);
}

// In-place per-block exclusive scan of counts[0..N); blocksums[b] = block total.
__global__ __launch_bounds__(256) void scanA_kernel(
    int* __restrict__ counts, int* __restrict__ blocksums, int N) {
  __shared__ int tmp[256];
  int tid = threadIdx.x;
  int i = blockIdx.x * 256 + tid;
  int v = (i < N) ? counts[i] : 0;
  tmp[tid] = v;
  __syncthreads();
  for (int off = 1; off < 256; off <<= 1) {
    int t = (tid >= off) ? tmp[tid - off] : 0;
    __syncthreads();
    tmp[tid] += t;
    __syncthreads();
  }
  if (i < N) counts[i] = tmp[tid] - v;  // exclusive
  if (tid == 255) blocksums[blockIdx.x] = tmp[tid];
}

__global__ __launch_bounds__(256) void scanB_kernel(
    int* __restrict__ blocksums, int nb) {
  __shared__ int tmp[256];
  int tid = threadIdx.x;
  int v = (tid < nb) ? blocksums[tid] : 0;
  tmp[tid] = v;
  __syncthreads();
  for (int off = 1; off < 256; off <<= 1) {
    int t = (tid >= off) ? tmp[tid - off] : 0;
    __syncthreads();
    tmp[tid] += t;
    __syncthreads();
  }
  if (tid < nb) blocksums[tid] = tmp[tid] - v;
}

__global__ __launch_bounds__(256) void scanC_kernel(
    int* __restrict__ offsets, int* __restrict__ cursor,
    const int* __restrict__ blocksums, int N, int E) {
  int i = blockIdx.x * 256 + threadIdx.x;
  if (i < N) {
    int o = offsets[i] + blocksums[blockIdx.x];
    offsets[i] = o;
    cursor[i] = o;
  }
  if (i == 0) offsets[N] = E;
}

// Degree histogram — LDS-aggregated (~45 hot global bins otherwise serialize).
__global__ __launch_bounds__(256) void deghist_kernel(
    const int* __restrict__ offsets, int* __restrict__ deg_hist, int N) {
  __shared__ int lhist[1024];
  for (int b = threadIdx.x; b < 1024; b += 256) lhist[b] = 0;
  __syncthreads();
  int i = blockIdx.x * 256 + threadIdx.x;
  if (i < N) {
    int d = min(offsets[i + 1] - offsets[i], 1023);
    atomicAdd(&lhist[d], 1);
  }
  __syncthreads();
  for (int b = threadIdx.x; b < 1024; b += 256) {
    int c = lhist[b];
    if (c) atomicAdd(&deg_hist[b], c);
  }
}

__global__ __launch_bounds__(256) void degscan_kernel(
    const int* __restrict__ deg_hist, int* __restrict__ deg_cursor) {
  __shared__ int tmp[256];
  int tid = threadIdx.x;
  int loc[4], s = 0;
#pragma unroll
  for (int k = 0; k < 4; ++k) { loc[k] = deg_hist[tid * 4 + k]; s += loc[k]; }
  tmp[tid] = s;
  __syncthreads();
  for (int off = 1; off < 256; off <<= 1) {
    int t = (tid >= off) ? tmp[tid - off] : 0;
    __syncthreads();
    tmp[tid] += t;
    __syncthreads();
  }
  int run = tmp[tid] - s;
#pragma unroll
  for (int k = 0; k < 4; ++k) { deg_cursor[tid * 4 + k] = run; run += loc[k]; }
}

// perm = rows grouped by degree — LDS-aggregated scatter.
__global__ __launch_bounds__(256) void degscatter_kernel(
    const int* __restrict__ offsets, int* __restrict__ deg_cursor,
    int* __restrict__ perm, int N) {
  __shared__ int lhist[1024];
  __shared__ int lbase[1024];
  for (int b = threadIdx.x; b < 1024; b += 256) lhist[b] = 0;
  __syncthreads();
  int i = blockIdx.x * 256 + threadIdx.x;
  int d = 0, lpos = 0;
  if (i < N) {
    d = min(offsets[i + 1] - offsets[i], 1023);
    lpos = atomicAdd(&lhist[d], 1);
  }
  __syncthreads();
  for (int b = threadIdx.x; b < 1024; b += 256) {
    int c = lhist[b];
    lbase[b] = c ? atomicAdd(&deg_cursor[b], c) : 0;
  }
  __syncthreads();
  if (i < N) perm[lbase[d] + lpos] = i;
}

__global__ __launch_bounds__(256) void edgescatter4_kernel(
    const int* __restrict__ src, const int* __restrict__ dst,
    int* __restrict__ cursor, int* __restrict__ sorted_src, int E4, int E) {
  int t = blockIdx.x * blockDim.x + threadIdx.x;
  if (t < E4) {
    int4 d = ((const int4*)dst)[t];
    int4 s = ((const int4*)src)[t];
    sorted_src[atomicAdd(&cursor[d.x], 1)] = s.x;
    sorted_src[atomicAdd(&cursor[d.y], 1)] = s.y;
    sorted_src[atomicAdd(&cursor[d.z], 1)] = s.z;
    sorted_src[atomicAdd(&cursor[d.w], 1)] = s.w;
  }
  int rem = E4 * 4 + t;
  if (t < E - E4 * 4) {
    int d = dst[rem];
    sorted_src[atomicAdd(&cursor[d], 1)] = src[rem];
  }
}

// ---------------- out[0] = normalize(x): one wave per row -------------------
// Also writes the bf16 mirror (mir may be null in fallback mode).
__global__ __launch_bounds__(256) void norm_kernel(
    const float* __restrict__ in, float* __restrict__ out,
    uint16_t* __restrict__ mir, int N) {
  int t = blockIdx.x * blockDim.x + threadIdx.x;
  int row = t >> 6;
  int lane = t & 63;
  if (row >= N) return;
  size_t base = (size_t)row * D + 2 * lane;
  float2 v = *(const float2*)(in + base);
  float ss = v.x * v.x + v.y * v.y;
#pragma unroll
  for (int off = 32; off > 0; off >>= 1) ss += __shfl_xor(ss, off);
  float denom = fmaxf(sqrtf(ss), 1e-12f);
  float2 o = make_float2(v.x / denom, v.y / denom);
  *(float2*)(out + base) = o;
  if (mir) {
    uint32_t w = f32_to_bf16_rne(o.x) | (f32_to_bf16_rne(o.y) << 16);
    *(uint32_t*)(mir + base) = w;
  }
}

// ---------------- Fused hop (bf16 gather): 8 lanes/row, 8 rows/wave ---------
union V16 { float4 v[4]; float f[16]; };
union U8 { uint4 v[2]; uint32_t u[8]; };

__device__ inline void cvt16(const U8& a, V16& af) {
#pragma unroll
  for (int i = 0; i < 8; ++i) {
    af.f[2 * i] = __uint_as_float(a.u[i] << 16);
    af.f[2 * i + 1] = __uint_as_float(a.u[i] & 0xffff0000u);
  }
}

__global__ __launch_bounds__(256) void hop_kernel_bf16(
    const float* __restrict__ hprev, const uint16_t* __restrict__ mprev,
    float* __restrict__ hout, uint16_t* __restrict__ mout,
    const int* __restrict__ offsets, const int* __restrict__ sorted_src,
    const int* __restrict__ perm, int N, uint32_t k0, uint32_t k1) {
  int g = (blockIdx.x * blockDim.x + threadIdx.x) >> 3;  // group = one dst row
  int sub = threadIdx.x & 7;                             // 8 lanes per row
  if (g >= N) return;
  int r = perm[g];
  size_t rbase = (size_t)r * D + sub * 16;

  V16 b;
  {
    const float4* p = (const float4*)(hprev + rbase);
    b.v[0] = p[0]; b.v[1] = p[1]; b.v[2] = p[2]; b.v[3] = p[3];
  }
  V16 acc;
#pragma unroll
  for (int i = 0; i < 16; ++i) acc.f[i] = 0.f;

  int j = offsets[r], jhi = offsets[r + 1];
  U8 a;
  if (j < jhi) {
    const uint4* p = (const uint4*)(mprev + (size_t)sorted_src[j] * D + sub * 16);
    a.v[0] = p[0]; a.v[1] = p[1];
  }
  while (j < jhi) {
    int jn = j + 1;
    U8 an;
    if (jn < jhi) {
      const uint4* p =
          (const uint4*)(mprev + (size_t)sorted_src[jn] * D + sub * 16);
      an.v[0] = p[0]; an.v[1] = p[1];
    }
    V16 af;
    cvt16(a, af);
    float part = af.f[0] * b.f[0];
#pragma unroll
    for (int i = 1; i < 16; ++i) part = fmaf(af.f[i], b.f[i], part);
    part += __shfl_xor(part, 1);
    part += __shfl_xor(part, 2);
    part += __shfl_xor(part, 4);
    float alpha = __builtin_amdgcn_rcpf(1.0f + __expf(-part));
#pragma unroll
    for (int i = 0; i < 16; ++i) acc.f[i] = fmaf(alpha, af.f[i], acc.f[i]);
    a = an;
    j = jn;
  }

  // noise (bit-exact jax.random.normal) + L2 normalize epilogue
  uint32_t idx = (uint32_t)rbase;
  float ss = 0.f;
#pragma unroll
  for (int i = 0; i < 16; ++i) {
    acc.f[i] += 0.1f * jax_normal_elem(k0, k1, idx + (uint32_t)i);
    ss = fmaf(acc.f[i], acc.f[i], ss);
  }
  ss += __shfl_xor(ss, 1);
  ss += __shfl_xor(ss, 2);
  ss += __shfl_xor(ss, 4);
  float denom = fmaxf(sqrtf(ss), 1e-12f);
#pragma unroll
  for (int i = 0; i < 16; ++i) acc.f[i] = acc.f[i] / denom;
  {
    float4* p = (float4*)(hout + rbase);
    p[0] = acc.v[0]; p[1] = acc.v[1]; p[2] = acc.v[2]; p[3] = acc.v[3];
  }
  if (mout) {
    U8 w;
#pragma unroll
    for (int i = 0; i < 8; ++i)
      w.u[i] = f32_to_bf16_rne(acc.f[2 * i]) |
               (f32_to_bf16_rne(acc.f[2 * i + 1]) << 16);
    uint4* p = (uint4*)(mout + rbase);
    p[0] = w.v[0]; p[1] = w.v[1];
  }
}

// ---------------- Fallback hop (f32 gather) — proven round-4 path -----------
__global__ __launch_bounds__(256) void hop_kernel_f32(
    const float* __restrict__ hprev, float* __restrict__ hout,
    const int* __restrict__ offsets, const int* __restrict__ sorted_src,
    const int* __restrict__ perm, int N, uint32_t k0, uint32_t k1) {
  int g = (blockIdx.x * blockDim.x + threadIdx.x) >> 3;
  int sub = threadIdx.x & 7;
  if (g >= N) return;
  int r = perm[g];
  size_t rbase = (size_t)r * D + sub * 16;

  V16 b;
  {
    const float4* p = (const float4*)(hprev + rbase);
    b.v[0] = p[0]; b.v[1] = p[1]; b.v[2] = p[2]; b.v[3] = p[3];
  }
  V16 acc;
#pragma unroll
  for (int i = 0; i < 16; ++i) acc.f[i] = 0.f;

  int j = offsets[r], jhi = offsets[r + 1];
  V16 a;
  if (j < jhi) {
    const float4* p = (const float4*)(hprev + (size_t)sorted_src[j] * D + sub * 16);
    a.v[0] = p[0]; a.v[1] = p[1]; a.v[2] = p[2]; a.v[3] = p[3];
  }
  while (j < jhi) {
    int jn = j + 1;
    V16 an;
    if (jn < jhi) {
      const float4* p = (const float4*)(hprev + (size_t)sorted_src[jn] * D + sub * 16);
      an.v[0] = p[0]; an.v[1] = p[1]; an.v[2] = p[2]; an.v[3] = p[3];
    }
    float part = a.f[0] * b.f[0];
#pragma unroll
    for (int i = 1; i < 16; ++i) part = fmaf(a.f[i], b.f[i], part);
    part += __shfl_xor(part, 1);
    part += __shfl_xor(part, 2);
    part += __shfl_xor(part, 4);
    float alpha = 1.0f / (1.0f + expf(-part));
#pragma unroll
    for (int i = 0; i < 16; ++i) acc.f[i] = fmaf(alpha, a.f[i], acc.f[i]);
    a = an;
    j = jn;
  }

  uint32_t idx = (uint32_t)rbase;
  float ss = 0.f;
#pragma unroll
  for (int i = 0; i < 16; ++i) {
    acc.f[i] += 0.1f * jax_normal_elem(k0, k1, idx + (uint32_t)i);
    ss = fmaf(acc.f[i], acc.f[i], ss);
  }
  ss += __shfl_xor(ss, 1);
  ss += __shfl_xor(ss, 2);
  ss += __shfl_xor(ss, 4);
  float denom = fmaxf(sqrtf(ss), 1e-12f);
#pragma unroll
  for (int i = 0; i < 16; ++i) acc.f[i] = acc.f[i] / denom;
  {
    float4* p = (float4*)(hout + rbase);
    p[0] = acc.v[0]; p[1] = acc.v[1]; p[2] = acc.v[2]; p[3] = acc.v[3];
  }
}

extern "C" void kernel_launch(void* const* d_in, const int* in_sizes, int n_in,
                              void* d_out, int out_size, void* d_ws, size_t ws_size,
                              hipStream_t stream) {
  const float* x = (const float*)d_in[0];
  const int* ei = (const int*)d_in[1];
  int N = in_sizes[0] / D;   // 50000
  int E = in_sizes[1] / 2;   // 800000
  const int* src = ei;
  const int* dst = ei + E;
  float* out = (float*)d_out;
  size_t ND = (size_t)N * D;

  int nblocksN = (N + 255) / 256;

  // ws layout (ints): offsets[N+1] | cursor[N] | perm[N] | deg_hist[1024]
  //                 | deg_cursor[1024] | blocksums[256] | sorted_src[E]
  //   then (256B aligned): bf16 mirrors mir0[N*D], mir1[N*D]
  int* offsets = (int*)d_ws;
  int* cursor = offsets + (N + 1);
  int* perm = cursor + N;
  int* deg_hist = perm + N;
  int* deg_cursor = deg_hist + 1024;
  int* blocksums = deg_cursor + 1024;
  int* sorted_src = blocksums + 256;
  size_t intWords = (size_t)(N + 1) + N + N + 1024 + 1024 + 256 + E;
  size_t mirOff = (intWords * 4 + 255) & ~(size_t)255;
  size_t need = mirOff + 2 * ND * sizeof(uint16_t);
  bool use_bf16 = ws_size >= need;
  uint16_t* mir0 = (uint16_t*)((char*)d_ws + mirOff);
  uint16_t* mir1 = mir0 + ND;

  // noise_keys = jax.random.split(jax.random.key(1), 3)  [threefry_partitionable]
  uint32_t nk0[3], nk1[3];
  for (int k = 0; k < 3; ++k)
    threefry2x32(0u, 1u, 0u, (uint32_t)k, &nk0[k], &nk1[k]);

  int E4 = E / 4;
  int e4Blocks = (max(E4, E - E4 * 4) + 255) / 256;
  int rowWaveBlocks = (int)(((size_t)N * 64 + 255) / 256);  // 1 wave/row (norm)
  int hopBlocks = (int)(((size_t)N * 8 + 255) / 256);       // 8 lanes/row (hop)

  // ---- CSR build + degree sort (reused by all 3 hops) ----
  hipMemsetAsync(offsets, 0, (size_t)(N + 1) * sizeof(int), stream);
  hipMemsetAsync(deg_hist, 0, 1024 * sizeof(int), stream);
  hipLaunchKernelGGL(hist4_kernel, dim3(e4Blocks), dim3(256), 0, stream,
                     dst, offsets, E4, E);
  hipLaunchKernelGGL(scanA_kernel, dim3(nblocksN), dim3(256), 0, stream,
                     offsets, blocksums, N);
  hipLaunchKernelGGL(scanB_kernel, dim3(1), dim3(256), 0, stream, blocksums, nblocksN);
  hipLaunchKernelGGL(scanC_kernel, dim3(nblocksN), dim3(256), 0, stream,
                     offsets, cursor, blocksums, N, E);
  hipLaunchKernelGGL(deghist_kernel, dim3(nblocksN), dim3(256), 0, stream,
                     offsets, deg_hist, N);
  hipLaunchKernelGGL(degscan_kernel, dim3(1), dim3(256), 0, stream,
                     deg_hist, deg_cursor);
  hipLaunchKernelGGL(degscatter_kernel, dim3(nblocksN), dim3(256), 0, stream,
                     offsets, deg_cursor, perm, N);
  hipLaunchKernelGGL(edgescatter4_kernel, dim3(e4Blocks), dim3(256), 0, stream,
                     src, dst, cursor, sorted_src, E4, E);

  // out[0] = normalize(x) (+ bf16 mirror)
  hipLaunchKernelGGL(norm_kernel, dim3(rowWaveBlocks), dim3(256), 0, stream,
                     x, out, use_bf16 ? mir0 : (uint16_t*)nullptr, N);

  if (use_bf16) {
    uint16_t* mirs[4] = {mir0, mir1, mir0, nullptr};  // last hop: no mirror out
    for (int k = 0; k < 3; ++k) {
      const float* hk = out + (size_t)k * ND;
      float* hk1 = out + (size_t)(k + 1) * ND;
      hipLaunchKernelGGL(hop_kernel_bf16, dim3(hopBlocks), dim3(256), 0, stream,
                         hk, mirs[k], hk1, mirs[k + 1], offsets, sorted_src,
                         perm, N, nk0[k], nk1[k]);
    }
  } else {
    for (int k = 0; k < 3; ++k) {
      const float* hk = out + (size_t)k * ND;
      float* hk1 = out + (size_t)(k + 1) * ND;
      hipLaunchKernelGGL(hop_kernel_f32, dim3(hopBlocks), dim3(256), 0, stream,
                         hk, hk1, offsets, sorted_src, perm, N, nk0[k], nk1[k]);
    }
  }
}

// Round 6
// 405.449 us; speedup vs baseline: 1.7738x; 1.0893x over previous
//
#include <hip/hip_runtime.h>
#include <cstdint>
#include <cstddef>

#define D 128

// ---------------- Threefry-2x32 (JAX/Random123), host+device ----------------
__host__ __device__ inline uint32_t rotl32(uint32_t v, int d) {
  return (v << d) | (v >> (32 - d));
}

__host__ __device__ inline void threefry2x32(uint32_t k0, uint32_t k1,
                                             uint32_t x0, uint32_t x1,
                                             uint32_t* o0, uint32_t* o1) {
  uint32_t k2 = k0 ^ k1 ^ 0x1BD11BDAu;
  x0 += k0; x1 += k1;
#define TF_RND(r) x0 += x1; x1 = rotl32(x1, (r)); x1 ^= x0;
  TF_RND(13) TF_RND(15) TF_RND(26) TF_RND(6)
  x0 += k1; x1 += k2 + 1u;
  TF_RND(17) TF_RND(29) TF_RND(16) TF_RND(24)
  x0 += k2; x1 += k0 + 2u;
  TF_RND(13) TF_RND(15) TF_RND(26) TF_RND(6)
  x0 += k0; x1 += k1 + 3u;
  TF_RND(17) TF_RND(29) TF_RND(16) TF_RND(24)
  x0 += k1; x1 += k2 + 4u;
  TF_RND(13) TF_RND(15) TF_RND(26) TF_RND(6)
  x0 += k2; x1 += k0 + 5u;
#undef TF_RND
  *o0 = x0; *o1 = x1;
}

// XLA ErfInv32 (Giles) — matches lax.erf_inv lowering for f32.
__device__ inline float erfinv_f32(float x) {
  float w = -log1pf(-x * x);
  float p;
  if (w < 5.0f) {
    w = w - 2.5f;
    p = 2.81022636e-08f;
    p = fmaf(p, w, 3.43273939e-07f);
    p = fmaf(p, w, -3.5233877e-06f);
    p = fmaf(p, w, -4.39150654e-06f);
    p = fmaf(p, w, 0.00021858087f);
    p = fmaf(p, w, -0.00125372503f);
    p = fmaf(p, w, -0.00417768164f);
    p = fmaf(p, w, 0.246640727f);
    p = fmaf(p, w, 1.50140941f);
  } else {
    w = sqrtf(w) - 3.0f;
    p = -0.000200214257f;
    p = fmaf(p, w, 0.000100950558f);
    p = fmaf(p, w, 0.00134934322f);
    p = fmaf(p, w, -0.00367342844f);
    p = fmaf(p, w, 0.00573950773f);
    p = fmaf(p, w, -0.0076224613f);
    p = fmaf(p, w, 0.00943887047f);
    p = fmaf(p, w, 1.00167406f);
    p = fmaf(p, w, 2.83297682f);
  }
  return p * x;
}

__device__ inline float jax_normal_elem(uint32_t k0, uint32_t k1, uint32_t idx) {
  uint32_t o0, o1;
  threefry2x32(k0, k1, 0u, idx, &o0, &o1);
  uint32_t bits = o0 ^ o1;
  float f = __uint_as_float((bits >> 9) | 0x3F800000u) - 1.0f;  // [0,1)
  float u = f * 2.0f + (-0.99999994f);
  u = fmaxf(-0.99999994f, u);
  return 1.41421356237309505f * erfinv_f32(u);
}

__device__ inline uint32_t f32_to_bf16_rne(float f) {
  uint32_t u = __float_as_uint(f);
  u += 0x7fffu + ((u >> 16) & 1u);
  return u >> 16;
}

// ---------------- CSR build -------------------------------------------------
__global__ __launch_bounds__(256) void hist4_kernel(
    const int* __restrict__ dst, int* __restrict__ counts, int E4, int E) {
  int t = blockIdx.x * blockDim.x + threadIdx.x;
  if (t < E4) {
    int4 d = ((const int4*)dst)[t];
    atomicAdd(&counts[d.x], 1);
    atomicAdd(&counts[d.y], 1);
    atomicAdd(&counts[d.z], 1);
    atomicAdd(&counts[d.w], 1);
  }
  int rem = E4 * 4 + t;
  if (t < E - E4 * 4) atomicAdd(&counts[dst[rem]], 1);
}

// In-place per-block exclusive scan of counts[0..N); blocksums[b] = block total.
__global__ __launch_bounds__(256) void scanA_kernel(
    int* __restrict__ counts, int* __restrict__ blocksums, int N) {
  __shared__ int tmp[256];
  int tid = threadIdx.x;
  int i = blockIdx.x * 256 + tid;
  int v = (i < N) ? counts[i] : 0;
  tmp[tid] = v;
  __syncthreads();
  for (int off = 1; off < 256; off <<= 1) {
    int t = (tid >= off) ? tmp[tid - off] : 0;
    __syncthreads();
    tmp[tid] += t;
    __syncthreads();
  }
  if (i < N) counts[i] = tmp[tid] - v;  // exclusive
  if (tid == 255) blocksums[blockIdx.x] = tmp[tid];
}

__global__ __launch_bounds__(256) void scanB_kernel(
    int* __restrict__ blocksums, int nb) {
  __shared__ int tmp[256];
  int tid = threadIdx.x;
  int v = (tid < nb) ? blocksums[tid] : 0;
  tmp[tid] = v;
  __syncthreads();
  for (int off = 1; off < 256; off <<= 1) {
    int t = (tid >= off) ? tmp[tid - off] : 0;
    __syncthreads();
    tmp[tid] += t;
    __syncthreads();
  }
  if (tid < nb) blocksums[tid] = tmp[tid] - v;
}

__global__ __launch_bounds__(256) void scanC_kernel(
    int* __restrict__ offsets, int* __restrict__ cursor,
    const int* __restrict__ blocksums, int N, int E) {
  int i = blockIdx.x * 256 + threadIdx.x;
  if (i < N) {
    int o = offsets[i] + blocksums[blockIdx.x];
    offsets[i] = o;
    cursor[i] = o;
  }
  if (i == 0) offsets[N] = E;
}

// Degree histogram — LDS-aggregated (~45 hot global bins otherwise serialize).
__global__ __launch_bounds__(256) void deghist_kernel(
    const int* __restrict__ offsets, int* __restrict__ deg_hist, int N) {
  __shared__ int lhist[1024];
  for (int b = threadIdx.x; b < 1024; b += 256) lhist[b] = 0;
  __syncthreads();
  int i = blockIdx.x * 256 + threadIdx.x;
  if (i < N) {
    int d = min(offsets[i + 1] - offsets[i], 1023);
    atomicAdd(&lhist[d], 1);
  }
  __syncthreads();
  for (int b = threadIdx.x; b < 1024; b += 256) {
    int c = lhist[b];
    if (c) atomicAdd(&deg_hist[b], c);
  }
}

__global__ __launch_bounds__(256) void degscan_kernel(
    const int* __restrict__ deg_hist, int* __restrict__ deg_cursor) {
  __shared__ int tmp[256];
  int tid = threadIdx.x;
  int loc[4], s = 0;
#pragma unroll
  for (int k = 0; k < 4; ++k) { loc[k] = deg_hist[tid * 4 + k]; s += loc[k]; }
  tmp[tid] = s;
  __syncthreads();
  for (int off = 1; off < 256; off <<= 1) {
    int t = (tid >= off) ? tmp[tid - off] : 0;
    __syncthreads();
    tmp[tid] += t;
    __syncthreads();
  }
  int run = tmp[tid] - s;
#pragma unroll
  for (int k = 0; k < 4; ++k) { deg_cursor[tid * 4 + k] = run; run += loc[k]; }
}

// perm = rows grouped by degree — LDS-aggregated scatter.
__global__ __launch_bounds__(256) void degscatter_kernel(
    const int* __restrict__ offsets, int* __restrict__ deg_cursor,
    int* __restrict__ perm, int N) {
  __shared__ int lhist[1024];
  __shared__ int lbase[1024];
  for (int b = threadIdx.x; b < 1024; b += 256) lhist[b] = 0;
  __syncthreads();
  int i = blockIdx.x * 256 + threadIdx.x;
  int d = 0, lpos = 0;
  if (i < N) {
    d = min(offsets[i + 1] - offsets[i], 1023);
    lpos = atomicAdd(&lhist[d], 1);
  }
  __syncthreads();
  for (int b = threadIdx.x; b < 1024; b += 256) {
    int c = lhist[b];
    lbase[b] = c ? atomicAdd(&deg_cursor[b], c) : 0;
  }
  __syncthreads();
  if (i < N) perm[lbase[d] + lpos] = i;
}

__global__ __launch_bounds__(256) void edgescatter4_kernel(
    const int* __restrict__ src, const int* __restrict__ dst,
    int* __restrict__ cursor, int* __restrict__ sorted_src, int E4, int E) {
  int t = blockIdx.x * blockDim.x + threadIdx.x;
  if (t < E4) {
    int4 d = ((const int4*)dst)[t];
    int4 s = ((const int4*)src)[t];
    sorted_src[atomicAdd(&cursor[d.x], 1)] = s.x;
    sorted_src[atomicAdd(&cursor[d.y], 1)] = s.y;
    sorted_src[atomicAdd(&cursor[d.z], 1)] = s.z;
    sorted_src[atomicAdd(&cursor[d.w], 1)] = s.w;
  }
  int rem = E4 * 4 + t;
  if (t < E - E4 * 4) {
    int d = dst[rem];
    sorted_src[atomicAdd(&cursor[d], 1)] = src[rem];
  }
}

// ---------------- out[0] = normalize(x): one wave per row -------------------
__global__ __launch_bounds__(256) void norm_kernel(
    const float* __restrict__ in, float* __restrict__ out,
    uint16_t* __restrict__ mir, int N) {
  int t = blockIdx.x * blockDim.x + threadIdx.x;
  int row = t >> 6;
  int lane = t & 63;
  if (row >= N) return;
  size_t base = (size_t)row * D + 2 * lane;
  float2 v = *(const float2*)(in + base);
  float ss = v.x * v.x + v.y * v.y;
#pragma unroll
  for (int off = 32; off > 0; off >>= 1) ss += __shfl_xor(ss, off);
  float denom = fmaxf(sqrtf(ss), 1e-12f);
  float2 o = make_float2(v.x / denom, v.y / denom);
  *(float2*)(out + base) = o;
  if (mir) {
    uint32_t w = f32_to_bf16_rne(o.x) | (f32_to_bf16_rne(o.y) << 16);
    *(uint32_t*)(mir + base) = w;
  }
}

// ---------------- Fused hop (bf16 gather): 16 lanes/row, 4 rows/wave --------
// MLP-oriented: row gathers prefetched 3 deep, indices 4 deep (clamped
// addresses so the pipeline needs no divergent guards).
union V8 { float4 v[2]; float f[8]; };
union U4B { uint4 v; uint32_t u[4]; };

__device__ inline void cvt8(const U4B& a, V8& af) {
#pragma unroll
  for (int i = 0; i < 4; ++i) {
    af.f[2 * i] = __uint_as_float(a.u[i] << 16);
    af.f[2 * i + 1] = __uint_as_float(a.u[i] & 0xffff0000u);
  }
}

__global__ __launch_bounds__(256) void hop_kernel_bf16(
    const float* __restrict__ hprev, const uint16_t* __restrict__ mprev,
    float* __restrict__ hout, uint16_t* __restrict__ mout,
    const int* __restrict__ offsets, const int* __restrict__ sorted_src,
    const int* __restrict__ perm, int N, int E, uint32_t k0, uint32_t k1) {
  int g = (blockIdx.x * blockDim.x + threadIdx.x) >> 4;  // one dst row / 16 lanes
  int sub = threadIdx.x & 15;                            // lane-in-row: 8 cols
  if (g >= N) return;
  int r = perm[g];
  size_t rbase = (size_t)r * D + sub * 8;

  V8 b;
  {
    const float4* p = (const float4*)(hprev + rbase);
    b.v[0] = p[0]; b.v[1] = p[1];
  }
  V8 acc;
#pragma unroll
  for (int i = 0; i < 8; ++i) acc.f[i] = 0.f;

  int j0 = offsets[r];
  int cnt = offsets[r + 1] - j0;
  int Em1 = E - 1;

  // index pipeline (4 deep) and row pipeline (3 deep), clamped addresses
  int s1 = sorted_src[min(j0 + 1, Em1)];
  int s2 = sorted_src[min(j0 + 2, Em1)];
  int s3 = sorted_src[min(j0 + 3, Em1)];
  U4B a0, a1, a2;
  {
    int s0 = sorted_src[min(j0, Em1)];
    a0.v = *(const uint4*)(mprev + (size_t)s0 * D + sub * 8);
  }
  a1.v = *(const uint4*)(mprev + (size_t)s1 * D + sub * 8);
  a2.v = *(const uint4*)(mprev + (size_t)s2 * D + sub * 8);

  for (int i = 0; i < cnt; ++i) {
    int s4 = sorted_src[min(j0 + i + 4, Em1)];
    U4B a3;
    a3.v = *(const uint4*)(mprev + (size_t)s3 * D + sub * 8);

    V8 af;
    cvt8(a0, af);
    float part = af.f[0] * b.f[0];
#pragma unroll
    for (int q = 1; q < 8; ++q) part = fmaf(af.f[q], b.f[q], part);
    part += __shfl_xor(part, 1);
    part += __shfl_xor(part, 2);
    part += __shfl_xor(part, 4);
    part += __shfl_xor(part, 8);
    float alpha = __builtin_amdgcn_rcpf(1.0f + __expf(-part));
#pragma unroll
    for (int q = 0; q < 8; ++q) acc.f[q] = fmaf(alpha, af.f[q], acc.f[q]);

    a0 = a1; a1 = a2; a2 = a3;
    s3 = s4;
  }

  // noise (bit-exact jax.random.normal) + L2 normalize epilogue
  uint32_t idx = (uint32_t)rbase;
  float ss = 0.f;
#pragma unroll
  for (int i = 0; i < 8; ++i) {
    acc.f[i] += 0.1f * jax_normal_elem(k0, k1, idx + (uint32_t)i);
    ss = fmaf(acc.f[i], acc.f[i], ss);
  }
  ss += __shfl_xor(ss, 1);
  ss += __shfl_xor(ss, 2);
  ss += __shfl_xor(ss, 4);
  ss += __shfl_xor(ss, 8);
  float denom = fmaxf(sqrtf(ss), 1e-12f);
#pragma unroll
  for (int i = 0; i < 8; ++i) acc.f[i] = acc.f[i] / denom;
  {
    float4* p = (float4*)(hout + rbase);
    p[0] = acc.v[0]; p[1] = acc.v[1];
  }
  if (mout) {
    U4B w;
#pragma unroll
    for (int i = 0; i < 4; ++i)
      w.u[i] = f32_to_bf16_rne(acc.f[2 * i]) |
               (f32_to_bf16_rne(acc.f[2 * i + 1]) << 16);
    *(uint4*)(mout + rbase) = w.v;
  }
}

// ---------------- Fallback hop (f32 gather) — proven round-4 path -----------
union V16 { float4 v[4]; float f[16]; };

__global__ __launch_bounds__(256) void hop_kernel_f32(
    const float* __restrict__ hprev, float* __restrict__ hout,
    const int* __restrict__ offsets, const int* __restrict__ sorted_src,
    const int* __restrict__ perm, int N, uint32_t k0, uint32_t k1) {
  int g = (blockIdx.x * blockDim.x + threadIdx.x) >> 3;
  int sub = threadIdx.x & 7;
  if (g >= N) return;
  int r = perm[g];
  size_t rbase = (size_t)r * D + sub * 16;

  V16 b;
  {
    const float4* p = (const float4*)(hprev + rbase);
    b.v[0] = p[0]; b.v[1] = p[1]; b.v[2] = p[2]; b.v[3] = p[3];
  }
  V16 acc;
#pragma unroll
  for (int i = 0; i < 16; ++i) acc.f[i] = 0.f;

  int j = offsets[r], jhi = offsets[r + 1];
  V16 a;
  if (j < jhi) {
    const float4* p = (const float4*)(hprev + (size_t)sorted_src[j] * D + sub * 16);
    a.v[0] = p[0]; a.v[1] = p[1]; a.v[2] = p[2]; a.v[3] = p[3];
  }
  while (j < jhi) {
    int jn = j + 1;
    V16 an;
    if (jn < jhi) {
      const float4* p = (const float4*)(hprev + (size_t)sorted_src[jn] * D + sub * 16);
      an.v[0] = p[0]; an.v[1] = p[1]; an.v[2] = p[2]; an.v[3] = p[3];
    }
    float part = a.f[0] * b.f[0];
#pragma unroll
    for (int i = 1; i < 16; ++i) part = fmaf(a.f[i], b.f[i], part);
    part += __shfl_xor(part, 1);
    part += __shfl_xor(part, 2);
    part += __shfl_xor(part, 4);
    float alpha = 1.0f / (1.0f + expf(-part));
#pragma unroll
    for (int i = 0; i < 16; ++i) acc.f[i] = fmaf(alpha, a.f[i], acc.f[i]);
    a = an;
    j = jn;
  }

  uint32_t idx = (uint32_t)rbase;
  float ss = 0.f;
#pragma unroll
  for (int i = 0; i < 16; ++i) {
    acc.f[i] += 0.1f * jax_normal_elem(k0, k1, idx + (uint32_t)i);
    ss = fmaf(acc.f[i], acc.f[i], ss);
  }
  ss += __shfl_xor(ss, 1);
  ss += __shfl_xor(ss, 2);
  ss += __shfl_xor(ss, 4);
  float denom = fmaxf(sqrtf(ss), 1e-12f);
#pragma unroll
  for (int i = 0; i < 16; ++i) acc.f[i] = acc.f[i] / denom;
  {
    float4* p = (float4*)(hout + rbase);
    p[0] = acc.v[0]; p[1] = acc.v[1]; p[2] = acc.v[2]; p[3] = acc.v[3];
  }
}

extern "C" void kernel_launch(void* const* d_in, const int* in_sizes, int n_in,
                              void* d_out, int out_size, void* d_ws, size_t ws_size,
                              hipStream_t stream) {
  const float* x = (const float*)d_in[0];
  const int* ei = (const int*)d_in[1];
  int N = in_sizes[0] / D;   // 50000
  int E = in_sizes[1] / 2;   // 800000
  const int* src = ei;
  const int* dst = ei + E;
  float* out = (float*)d_out;
  size_t ND = (size_t)N * D;

  int nblocksN = (N + 255) / 256;

  // ws layout (ints): offsets[N+1] | cursor[N] | perm[N] | deg_hist[1024]
  //                 | deg_cursor[1024] | blocksums[256] | sorted_src[E]
  //   then (256B aligned): bf16 mirrors mir0[N*D], mir1[N*D]
  int* offsets = (int*)d_ws;
  int* cursor = offsets + (N + 1);
  int* perm = cursor + N;
  int* deg_hist = perm + N;
  int* deg_cursor = deg_hist + 1024;
  int* blocksums = deg_cursor + 1024;
  int* sorted_src = blocksums + 256;
  size_t intWords = (size_t)(N + 1) + N + N + 1024 + 1024 + 256 + E;
  size_t mirOff = (intWords * 4 + 255) & ~(size_t)255;
  size_t need = mirOff + 2 * ND * sizeof(uint16_t);
  bool use_bf16 = ws_size >= need;
  uint16_t* mir0 = (uint16_t*)((char*)d_ws + mirOff);
  uint16_t* mir1 = mir0 + ND;

  // noise_keys = jax.random.split(jax.random.key(1), 3)  [threefry_partitionable]
  uint32_t nk0[3], nk1[3];
  for (int k = 0; k < 3; ++k)
    threefry2x32(0u, 1u, 0u, (uint32_t)k, &nk0[k], &nk1[k]);

  int E4 = E / 4;
  int e4Blocks = (max(E4, E - E4 * 4) + 255) / 256;
  int rowWaveBlocks = (int)(((size_t)N * 64 + 255) / 256);  // 1 wave/row (norm)
  int hopBlocks16 = (int)(((size_t)N * 16 + 255) / 256);    // 16 lanes/row (bf16 hop)
  int hopBlocks8 = (int)(((size_t)N * 8 + 255) / 256);      // 8 lanes/row (f32 hop)

  // ---- CSR build + degree sort (reused by all 3 hops) ----
  hipMemsetAsync(offsets, 0, (size_t)(N + 1) * sizeof(int), stream);
  hipMemsetAsync(deg_hist, 0, 1024 * sizeof(int), stream);
  hipLaunchKernelGGL(hist4_kernel, dim3(e4Blocks), dim3(256), 0, stream,
                     dst, offsets, E4, E);
  hipLaunchKernelGGL(scanA_kernel, dim3(nblocksN), dim3(256), 0, stream,
                     offsets, blocksums, N);
  hipLaunchKernelGGL(scanB_kernel, dim3(1), dim3(256), 0, stream, blocksums, nblocksN);
  hipLaunchKernelGGL(scanC_kernel, dim3(nblocksN), dim3(256), 0, stream,
                     offsets, cursor, blocksums, N, E);
  hipLaunchKernelGGL(deghist_kernel, dim3(nblocksN), dim3(256), 0, stream,
                     offsets, deg_hist, N);
  hipLaunchKernelGGL(degscan_kernel, dim3(1), dim3(256), 0, stream,
                     deg_hist, deg_cursor);
  hipLaunchKernelGGL(degscatter_kernel, dim3(nblocksN), dim3(256), 0, stream,
                     offsets, deg_cursor, perm, N);
  hipLaunchKernelGGL(edgescatter4_kernel, dim3(e4Blocks), dim3(256), 0, stream,
                     src, dst, cursor, sorted_src, E4, E);

  // out[0] = normalize(x) (+ bf16 mirror)
  hipLaunchKernelGGL(norm_kernel, dim3(rowWaveBlocks), dim3(256), 0, stream,
                     x, out, use_bf16 ? mir0 : (uint16_t*)nullptr, N);

  if (use_bf16) {
    uint16_t* mirs[4] = {mir0, mir1, mir0, nullptr};  // last hop: no mirror out
    for (int k = 0; k < 3; ++k) {
      const float* hk = out + (size_t)k * ND;
      float* hk1 = out + (size_t)(k + 1) * ND;
      hipLaunchKernelGGL(hop_kernel_bf16, dim3(hopBlocks16), dim3(256), 0, stream,
                         hk, mirs[k], hk1, mirs[k + 1], offsets, sorted_src,
                         perm, N, E, nk0[k], nk1[k]);
    }
  } else {
    for (int k = 0; k < 3; ++k) {
      const float* hk = out + (size_t)k * ND;
      float* hk1 = out + (size_t)(k + 1) * ND;
      hipLaunchKernelGGL(hop_kernel_f32, dim3(hopBlocks8), dim3(256), 0, stream,
                         hk, hk1, offsets, sorted_src, perm, N, nk0[k], nk1[k]);
    }
  }
}

// Round 7
// 386.901 us; speedup vs baseline: 1.8589x; 1.0479x over previous
//
#include <hip/hip_runtime.h>
#include <cstdint>
#include <cstddef>

#define D 128

// ---------------- Threefry-2x32 (JAX/Random123), host+device ----------------
__host__ __device__ inline uint32_t rotl32(uint32_t v, int d) {
  return (v << d) | (v >> (32 - d));
}

__host__ __device__ inline void threefry2x32(uint32_t k0, uint32_t k1,
                                             uint32_t x0, uint32_t x1,
                                             uint32_t* o0, uint32_t* o1) {
  uint32_t k2 = k0 ^ k1 ^ 0x1BD11BDAu;
  x0 += k0; x1 += k1;
#define TF_RND(r) x0 += x1; x1 = rotl32(x1, (r)); x1 ^= x0;
  TF_RND(13) TF_RND(15) TF_RND(26) TF_RND(6)
  x0 += k1; x1 += k2 + 1u;
  TF_RND(17) TF_RND(29) TF_RND(16) TF_RND(24)
  x0 += k2; x1 += k0 + 2u;
  TF_RND(13) TF_RND(15) TF_RND(26) TF_RND(6)
  x0 += k0; x1 += k1 + 3u;
  TF_RND(17) TF_RND(29) TF_RND(16) TF_RND(24)
  x0 += k1; x1 += k2 + 4u;
  TF_RND(13) TF_RND(15) TF_RND(26) TF_RND(6)
  x0 += k2; x1 += k0 + 5u;
#undef TF_RND
  *o0 = x0; *o1 = x1;
}

// XLA ErfInv32 (Giles) — matches lax.erf_inv lowering for f32.
__device__ inline float erfinv_f32(float x) {
  float w = -log1pf(-x * x);
  float p;
  if (w < 5.0f) {
    w = w - 2.5f;
    p = 2.81022636e-08f;
    p = fmaf(p, w, 3.43273939e-07f);
    p = fmaf(p, w, -3.5233877e-06f);
    p = fmaf(p, w, -4.39150654e-06f);
    p = fmaf(p, w, 0.00021858087f);
    p = fmaf(p, w, -0.00125372503f);
    p = fmaf(p, w, -0.00417768164f);
    p = fmaf(p, w, 0.246640727f);
    p = fmaf(p, w, 1.50140941f);
  } else {
    w = sqrtf(w) - 3.0f;
    p = -0.000200214257f;
    p = fmaf(p, w, 0.000100950558f);
    p = fmaf(p, w, 0.00134934322f);
    p = fmaf(p, w, -0.00367342844f);
    p = fmaf(p, w, 0.00573950773f);
    p = fmaf(p, w, -0.0076224613f);
    p = fmaf(p, w, 0.00943887047f);
    p = fmaf(p, w, 1.00167406f);
    p = fmaf(p, w, 2.83297682f);
  }
  return p * x;
}

__device__ inline float jax_normal_elem(uint32_t k0, uint32_t k1, uint32_t idx) {
  uint32_t o0, o1;
  threefry2x32(k0, k1, 0u, idx, &o0, &o1);
  uint32_t bits = o0 ^ o1;
  float f = __uint_as_float((bits >> 9) | 0x3F800000u) - 1.0f;  // [0,1)
  float u = f * 2.0f + (-0.99999994f);
  u = fmaxf(-0.99999994f, u);
  return 1.41421356237309505f * erfinv_f32(u);
}

__device__ inline uint32_t f32_to_bf16_rne(float f) {
  uint32_t u = __float_as_uint(f);
  u += 0x7fffu + ((u >> 16) & 1u);
  return u >> 16;
}

// ---------------- CSR build -------------------------------------------------
// Also zeroes deg_hist (block 0) ahead of scanA's fused degree-histogram.
__global__ __launch_bounds__(256) void hist4_kernel(
    const int* __restrict__ dst, int* __restrict__ counts,
    int* __restrict__ deg_hist, int E4, int E) {
  if (blockIdx.x == 0) {
    for (int b = threadIdx.x; b < 1024; b += 256) deg_hist[b] = 0;
  }
  int t = blockIdx.x * blockDim.x + threadIdx.x;
  if (t < E4) {
    int4 d = ((const int4*)dst)[t];
    atomicAdd(&counts[d.x], 1);
    atomicAdd(&counts[d.y], 1);
    atomicAdd(&counts[d.z], 1);
    atomicAdd(&counts[d.w], 1);
  }
  int rem = E4 * 4 + t;
  if (t < E - E4 * 4) atomicAdd(&counts[dst[rem]], 1);
}

// Per-block exclusive scan of counts (in place) + save degree + LDS-aggregated
// degree histogram (pre-scan counts[i] IS the degree).
__global__ __launch_bounds__(256) void scanA_kernel(
    int* __restrict__ counts, int* __restrict__ blocksums,
    int* __restrict__ deg, int* __restrict__ deg_hist, int N) {
  __shared__ int tmp[256];
  __shared__ int lhist[1024];
  for (int b = threadIdx.x; b < 1024; b += 256) lhist[b] = 0;
  int tid = threadIdx.x;
  int i = blockIdx.x * 256 + tid;
  int v = (i < N) ? counts[i] : 0;
  tmp[tid] = v;
  __syncthreads();
  if (i < N) {
    deg[i] = v;
    atomicAdd(&lhist[min(v, 1023)], 1);
  }
  for (int off = 1; off < 256; off <<= 1) {
    int t = (tid >= off) ? tmp[tid - off] : 0;
    __syncthreads();
    tmp[tid] += t;
    __syncthreads();
  }
  if (i < N) counts[i] = tmp[tid] - v;  // exclusive
  if (tid == 255) blocksums[blockIdx.x] = tmp[tid];
  __syncthreads();
  for (int b = threadIdx.x; b < 1024; b += 256) {
    int c = lhist[b];
    if (c) atomicAdd(&deg_hist[b], c);
  }
}

// Single block: exclusive scan of blocksums[nb] + exclusive scan of the
// 1024-bin degree histogram -> deg_cursor.
__global__ __launch_bounds__(256) void scanB_kernel(
    int* __restrict__ blocksums, int nb,
    const int* __restrict__ deg_hist, int* __restrict__ deg_cursor) {
  __shared__ int tmp[256];
  int tid = threadIdx.x;
  int v = (tid < nb) ? blocksums[tid] : 0;
  tmp[tid] = v;
  __syncthreads();
  for (int off = 1; off < 256; off <<= 1) {
    int t = (tid >= off) ? tmp[tid - off] : 0;
    __syncthreads();
    tmp[tid] += t;
    __syncthreads();
  }
  if (tid < nb) blocksums[tid] = tmp[tid] - v;
  __syncthreads();
  // degree-histogram scan: 4 bins/thread
  int loc[4], s = 0;
#pragma unroll
  for (int k = 0; k < 4; ++k) { loc[k] = deg_hist[tid * 4 + k]; s += loc[k]; }
  __syncthreads();
  tmp[tid] = s;
  __syncthreads();
  for (int off = 1; off < 256; off <<= 1) {
    int t = (tid >= off) ? tmp[tid - off] : 0;
    __syncthreads();
    tmp[tid] += t;
    __syncthreads();
  }
  int run = tmp[tid] - s;
#pragma unroll
  for (int k = 0; k < 4; ++k) { deg_cursor[tid * 4 + k] = run; run += loc[k]; }
}

// Finish offsets (+ blocksums), copy cursor, offsets[N]=E, and do the
// LDS-aggregated degree-grouping scatter (perm).
__global__ __launch_bounds__(256) void scanC_kernel(
    int* __restrict__ offsets, int* __restrict__ cursor,
    const int* __restrict__ blocksums, const int* __restrict__ deg,
    int* __restrict__ deg_cursor, int* __restrict__ perm, int N, int E) {
  __shared__ int lhist[1024];
  __shared__ int lbase[1024];
  for (int b = threadIdx.x; b < 1024; b += 256) lhist[b] = 0;
  __syncthreads();
  int i = blockIdx.x * 256 + threadIdx.x;
  int d = 0, lpos = 0;
  if (i < N) {
    int o = offsets[i] + blocksums[blockIdx.x];
    offsets[i] = o;
    cursor[i] = o;
    d = min(deg[i], 1023);
    lpos = atomicAdd(&lhist[d], 1);
  }
  if (i == 0) offsets[N] = E;
  __syncthreads();
  for (int b = threadIdx.x; b < 1024; b += 256) {
    int c = lhist[b];
    lbase[b] = c ? atomicAdd(&deg_cursor[b], c) : 0;
  }
  __syncthreads();
  if (i < N) perm[lbase[d] + lpos] = i;
}

__global__ __launch_bounds__(256) void edgescatter4_kernel(
    const int* __restrict__ src, const int* __restrict__ dst,
    int* __restrict__ cursor, int* __restrict__ sorted_src, int E4, int E) {
  int t = blockIdx.x * blockDim.x + threadIdx.x;
  if (t < E4) {
    int4 d = ((const int4*)dst)[t];
    int4 s = ((const int4*)src)[t];
    sorted_src[atomicAdd(&cursor[d.x], 1)] = s.x;
    sorted_src[atomicAdd(&cursor[d.y], 1)] = s.y;
    sorted_src[atomicAdd(&cursor[d.z], 1)] = s.z;
    sorted_src[atomicAdd(&cursor[d.w], 1)] = s.w;
  }
  int rem = E4 * 4 + t;
  if (t < E - E4 * 4) {
    int d = dst[rem];
    sorted_src[atomicAdd(&cursor[d], 1)] = src[rem];
  }
}

// ---------------- out[0] = normalize(x): one wave per row -------------------
__global__ __launch_bounds__(256) void norm_kernel(
    const float* __restrict__ in, float* __restrict__ out,
    uint16_t* __restrict__ mir, int N) {
  int t = blockIdx.x * blockDim.x + threadIdx.x;
  int row = t >> 6;
  int lane = t & 63;
  if (row >= N) return;
  size_t base = (size_t)row * D + 2 * lane;
  float2 v = *(const float2*)(in + base);
  float ss = v.x * v.x + v.y * v.y;
#pragma unroll
  for (int off = 32; off > 0; off >>= 1) ss += __shfl_xor(ss, off);
  float denom = fmaxf(sqrtf(ss), 1e-12f);
  float2 o = make_float2(v.x / denom, v.y / denom);
  *(float2*)(out + base) = o;
  if (mir) {
    uint32_t w = f32_to_bf16_rne(o.x) | (f32_to_bf16_rne(o.y) << 16);
    *(uint32_t*)(mir + base) = w;
  }
}

// ---------------- Fused hop (bf16 gather): 16 lanes/row, 4 rows/wave --------
// Rotating-buffer unroll-by-4: depth-4 row MLP, index prefetch one group
// ahead, zero register shifting. __launch_bounds__(256,4) gives the
// allocator room (<=128 VGPR) so the pipeline isn't collapsed.
union V8 { float4 v[2]; float f[8]; };
union U4B { uint4 v; uint32_t u[4]; };

__device__ inline void hop_edge(const U4B& raw, const V8& b, V8& acc) {
  V8 af;
#pragma unroll
  for (int i = 0; i < 4; ++i) {
    af.f[2 * i] = __uint_as_float(raw.u[i] << 16);
    af.f[2 * i + 1] = __uint_as_float(raw.u[i] & 0xffff0000u);
  }
  float part = af.f[0] * b.f[0];
#pragma unroll
  for (int q = 1; q < 8; ++q) part = fmaf(af.f[q], b.f[q], part);
  part += __shfl_xor(part, 1);
  part += __shfl_xor(part, 2);
  part += __shfl_xor(part, 4);
  part += __shfl_xor(part, 8);
  float alpha = __builtin_amdgcn_rcpf(1.0f + __expf(-part));
#pragma unroll
  for (int q = 0; q < 8; ++q) acc.f[q] = fmaf(alpha, af.f[q], acc.f[q]);
}

__global__ __launch_bounds__(256, 4) void hop_kernel_bf16(
    const float* __restrict__ hprev, const uint16_t* __restrict__ mprev,
    float* __restrict__ hout, uint16_t* __restrict__ mout,
    const int* __restrict__ offsets, const int* __restrict__ sorted_src,
    const int* __restrict__ perm, int N, int E, uint32_t k0, uint32_t k1) {
  int g = (blockIdx.x * blockDim.x + threadIdx.x) >> 4;  // one dst row / 16 lanes
  int sub = threadIdx.x & 15;                            // 8 cols per lane
  if (g >= N) return;
  int r = perm[g];
  size_t rbase = (size_t)r * D + sub * 8;

  V8 b;
  {
    const float4* p = (const float4*)(hprev + rbase);
    b.v[0] = p[0]; b.v[1] = p[1];
  }
  V8 acc;
#pragma unroll
  for (int i = 0; i < 8; ++i) acc.f[i] = 0.f;

  int j0 = offsets[r];
  int cnt = offsets[r + 1] - j0;
  int Em1 = E - 1;
  const uint16_t* mp = mprev + sub * 8;

  U4B buf[4];
  int sNext[4];
  // prologue: rows 0..3 into buf, indices for rows 4..7 into sNext
#pragma unroll
  for (int q = 0; q < 4; ++q) {
    int s = sorted_src[min(j0 + q, Em1)];
    buf[q].v = *(const uint4*)(mp + (size_t)s * D);
  }
#pragma unroll
  for (int q = 0; q < 4; ++q) sNext[q] = sorted_src[min(j0 + 4 + q, Em1)];

  int cnt4 = cnt & ~3;
  int i = 0;
  for (; i < cnt4; i += 4) {
#pragma unroll
    for (int q = 0; q < 4; ++q) {
      hop_edge(buf[q], b, acc);                                  // row i+q
      buf[q].v = *(const uint4*)(mp + (size_t)sNext[q] * D);     // row i+4+q
      sNext[q] = sorted_src[min(j0 + i + 8 + q, Em1)];           // row i+8+q
    }
  }
  // tail: buf[q] holds row cnt4+q
  int rem = cnt - cnt4;
#pragma unroll
  for (int q = 0; q < 3; ++q)
    if (q < rem) hop_edge(buf[q], b, acc);

  // noise (bit-exact jax.random.normal) + L2 normalize epilogue
  uint32_t idx = (uint32_t)rbase;
  float ss = 0.f;
#pragma unroll
  for (int i2 = 0; i2 < 8; ++i2) {
    acc.f[i2] += 0.1f * jax_normal_elem(k0, k1, idx + (uint32_t)i2);
    ss = fmaf(acc.f[i2], acc.f[i2], ss);
  }
  ss += __shfl_xor(ss, 1);
  ss += __shfl_xor(ss, 2);
  ss += __shfl_xor(ss, 4);
  ss += __shfl_xor(ss, 8);
  float denom = fmaxf(sqrtf(ss), 1e-12f);
#pragma unroll
  for (int i2 = 0; i2 < 8; ++i2) acc.f[i2] = acc.f[i2] / denom;
  {
    float4* p = (float4*)(hout + rbase);
    p[0] = acc.v[0]; p[1] = acc.v[1];
  }
  if (mout) {
    U4B w;
#pragma unroll
    for (int i2 = 0; i2 < 4; ++i2)
      w.u[i2] = f32_to_bf16_rne(acc.f[2 * i2]) |
                (f32_to_bf16_rne(acc.f[2 * i2 + 1]) << 16);
    *(uint4*)(mout + rbase) = w.v;
  }
}

// ---------------- Fallback hop (f32 gather) — proven round-4 path -----------
union V16 { float4 v[4]; float f[16]; };

__global__ __launch_bounds__(256) void hop_kernel_f32(
    const float* __restrict__ hprev, float* __restrict__ hout,
    const int* __restrict__ offsets, const int* __restrict__ sorted_src,
    const int* __restrict__ perm, int N, uint32_t k0, uint32_t k1) {
  int g = (blockIdx.x * blockDim.x + threadIdx.x) >> 3;
  int sub = threadIdx.x & 7;
  if (g >= N) return;
  int r = perm[g];
  size_t rbase = (size_t)r * D + sub * 16;

  V16 b;
  {
    const float4* p = (const float4*)(hprev + rbase);
    b.v[0] = p[0]; b.v[1] = p[1]; b.v[2] = p[2]; b.v[3] = p[3];
  }
  V16 acc;
#pragma unroll
  for (int i = 0; i < 16; ++i) acc.f[i] = 0.f;

  int j = offsets[r], jhi = offsets[r + 1];
  V16 a;
  if (j < jhi) {
    const float4* p = (const float4*)(hprev + (size_t)sorted_src[j] * D + sub * 16);
    a.v[0] = p[0]; a.v[1] = p[1]; a.v[2] = p[2]; a.v[3] = p[3];
  }
  while (j < jhi) {
    int jn = j + 1;
    V16 an;
    if (jn < jhi) {
      const float4* p = (const float4*)(hprev + (size_t)sorted_src[jn] * D + sub * 16);
      an.v[0] = p[0]; an.v[1] = p[1]; an.v[2] = p[2]; an.v[3] = p[3];
    }
    float part = a.f[0] * b.f[0];
#pragma unroll
    for (int i = 1; i < 16; ++i) part = fmaf(a.f[i], b.f[i], part);
    part += __shfl_xor(part, 1);
    part += __shfl_xor(part, 2);
    part += __shfl_xor(part, 4);
    float alpha = 1.0f / (1.0f + expf(-part));
#pragma unroll
    for (int i = 0; i < 16; ++i) acc.f[i] = fmaf(alpha, a.f[i], acc.f[i]);
    a = an;
    j = jn;
  }

  uint32_t idx = (uint32_t)rbase;
  float ss = 0.f;
#pragma unroll
  for (int i = 0; i < 16; ++i) {
    acc.f[i] += 0.1f * jax_normal_elem(k0, k1, idx + (uint32_t)i);
    ss = fmaf(acc.f[i], acc.f[i], ss);
  }
  ss += __shfl_xor(ss, 1);
  ss += __shfl_xor(ss, 2);
  ss += __shfl_xor(ss, 4);
  float denom = fmaxf(sqrtf(ss), 1e-12f);
#pragma unroll
  for (int i = 0; i < 16; ++i) acc.f[i] = acc.f[i] / denom;
  {
    float4* p = (float4*)(hout + rbase);
    p[0] = acc.v[0]; p[1] = acc.v[1]; p[2] = acc.v[2]; p[3] = acc.v[3];
  }
}

extern "C" void kernel_launch(void* const* d_in, const int* in_sizes, int n_in,
                              void* d_out, int out_size, void* d_ws, size_t ws_size,
                              hipStream_t stream) {
  const float* x = (const float*)d_in[0];
  const int* ei = (const int*)d_in[1];
  int N = in_sizes[0] / D;   // 50000
  int E = in_sizes[1] / 2;   // 800000
  const int* src = ei;
  const int* dst = ei + E;
  float* out = (float*)d_out;
  size_t ND = (size_t)N * D;

  int nblocksN = (N + 255) / 256;

  // ws layout (ints): offsets[N+1] | cursor[N] | perm[N] | deg[N]
  //                 | deg_hist[1024] | deg_cursor[1024] | blocksums[256]
  //                 | sorted_src[E]
  //   then (256B aligned): bf16 mirrors mir0[N*D], mir1[N*D]
  int* offsets = (int*)d_ws;
  int* cursor = offsets + (N + 1);
  int* perm = cursor + N;
  int* deg = perm + N;
  int* deg_hist = deg + N;
  int* deg_cursor = deg_hist + 1024;
  int* blocksums = deg_cursor + 1024;
  int* sorted_src = blocksums + 256;
  size_t intWords = (size_t)(N + 1) + N + N + N + 1024 + 1024 + 256 + E;
  size_t mirOff = (intWords * 4 + 255) & ~(size_t)255;
  size_t need = mirOff + 2 * ND * sizeof(uint16_t);
  bool use_bf16 = ws_size >= need;
  uint16_t* mir0 = (uint16_t*)((char*)d_ws + mirOff);
  uint16_t* mir1 = mir0 + ND;

  // noise_keys = jax.random.split(jax.random.key(1), 3)  [threefry_partitionable]
  uint32_t nk0[3], nk1[3];
  for (int k = 0; k < 3; ++k)
    threefry2x32(0u, 1u, 0u, (uint32_t)k, &nk0[k], &nk1[k]);

  int E4 = E / 4;
  int e4Blocks = (max(E4, E - E4 * 4) + 255) / 256;
  int rowWaveBlocks = (int)(((size_t)N * 64 + 255) / 256);  // 1 wave/row (norm)
  int hopBlocks16 = (int)(((size_t)N * 16 + 255) / 256);    // 16 lanes/row (bf16 hop)
  int hopBlocks8 = (int)(((size_t)N * 8 + 255) / 256);      // 8 lanes/row (f32 hop)

  // ---- CSR build + degree sort (fused; reused by all 3 hops) ----
  hipMemsetAsync(offsets, 0, (size_t)(N + 1) * sizeof(int), stream);
  hipLaunchKernelGGL(hist4_kernel, dim3(e4Blocks), dim3(256), 0, stream,
                     dst, offsets, deg_hist, E4, E);
  hipLaunchKernelGGL(scanA_kernel, dim3(nblocksN), dim3(256), 0, stream,
                     offsets, blocksums, deg, deg_hist, N);
  hipLaunchKernelGGL(scanB_kernel, dim3(1), dim3(256), 0, stream,
                     blocksums, nblocksN, deg_hist, deg_cursor);
  hipLaunchKernelGGL(scanC_kernel, dim3(nblocksN), dim3(256), 0, stream,
                     offsets, cursor, blocksums, deg, deg_cursor, perm, N, E);
  hipLaunchKernelGGL(edgescatter4_kernel, dim3(e4Blocks), dim3(256), 0, stream,
                     src, dst, cursor, sorted_src, E4, E);

  // out[0] = normalize(x) (+ bf16 mirror)
  hipLaunchKernelGGL(norm_kernel, dim3(rowWaveBlocks), dim3(256), 0, stream,
                     x, out, use_bf16 ? mir0 : (uint16_t*)nullptr, N);

  if (use_bf16) {
    uint16_t* mirs[4] = {mir0, mir1, mir0, nullptr};  // last hop: no mirror out
    for (int k = 0; k < 3; ++k) {
      const float* hk = out + (size_t)k * ND;
      float* hk1 = out + (size_t)(k + 1) * ND;
      hipLaunchKernelGGL(hop_kernel_bf16, dim3(hopBlocks16), dim3(256), 0, stream,
                         hk, mirs[k], hk1, mirs[k + 1], offsets, sorted_src,
                         perm, N, E, nk0[k], nk1[k]);
    }
  } else {
    for (int k = 0; k < 3; ++k) {
      const float* hk = out + (size_t)k * ND;
      float* hk1 = out + (size_t)(k + 1) * ND;
      hipLaunchKernelGGL(hop_kernel_f32, dim3(hopBlocks8), dim3(256), 0, stream,
                         hk, hk1, offsets, sorted_src, perm, N, nk0[k], nk1[k]);
    }
  }
}